// Round 4
// baseline (1538.086 us; speedup 1.0000x reference)
//
#include <hip/hip_runtime.h>
#include <stdint.h>

// MemoryModule: z[N=65536,D=256], memory[M=2000,D=256] (fp32)
//   z_norm, m_norm = row-L2-normalize (eps added to norm)
//   sim = z_norm @ m_norm^T; w = softmax(sim, axis=1)
//   w2 = relu(w-lamb)*w/(|w-lamb|+1e-12); w_hat = w2/(sum w2 + 1e-12)
//   z_hat = w_hat @ memory
// d_out = [z_hat (N*D) | w_hat (N*M)] fp32
//
// R3: R2's 2-sweep recompute + nontemporal stores (bypass L2 alloc for the
// 524MB w_hat stream), occupancy 3->5 blocks/CU (zacc moved out of LDS into
// a never-taken global-atomic cold path), clean hot loop (no atomics).
// Softmax max-subtraction dropped: |sim|<=1 (cosine), exp in [e^-1, e].

typedef float  f32x4  __attribute__((ext_vector_type(4)));
typedef __bf16 bf16x8 __attribute__((ext_vector_type(8)));

#define DDIM 256
#define MDIM 2000
#define MT   125          // 2000 / 16 m-tiles
#define MPAD 2048
#define NROWS 32          // z-rows per block (2 row-groups of 16)
#define LAMB 0.002f
#define EPS_NORM 1e-10f
#define EPS_SHRINK 1e-12f

// ---------------- kernel 1: memory -> bf16 m_norm (padded to MPAD rows) ----
__global__ __launch_bounds__(256) void norm_mem_k(const float* __restrict__ mem,
                                                  __bf16* __restrict__ mnorm) {
  const int row = blockIdx.x;
  const int t   = threadIdx.x;
  if (row >= MDIM) { mnorm[(size_t)row * DDIM + t] = (__bf16)0.0f; return; }
  float x = mem[(size_t)row * DDIM + t];
  float s = x * x;
  #pragma unroll
  for (int m = 1; m < 64; m <<= 1) s += __shfl_xor(s, m, 64);
  __shared__ float wsum[4];
  if ((t & 63) == 0) wsum[t >> 6] = s;
  __syncthreads();
  s = wsum[0] + wsum[1] + wsum[2] + wsum[3];
  const float scale = 1.0f / (sqrtf(s) + EPS_NORM);
  mnorm[(size_t)row * DDIM + t] = (__bf16)(x * scale);
}

// ---------------- kernel 2: fused, 32 rows/block, 2 sweeps ----------------
// 4 waves split 125 m-tiles contiguously (32 per wave). Each tile:
// B[8] (16 rows x K=256 bf16) from L2, MFMA vs 2 row-group A-frags (regs).
// MFMA C layout (16x16x32): col = lane&15 (m), row = quad*4 + reg (n).
__global__ __launch_bounds__(256, 5) void fused_k(
    const float* __restrict__ z, const __bf16* __restrict__ mnorm,
    const float* __restrict__ mem, float* __restrict__ outz,
    float* __restrict__ outw) {
  __shared__ __bf16 zs[NROWS][264];      // z_norm staging (+8 pad)  16.9 KB
  __shared__ float  red[4][NROWS];       // cross-wave row reduction
  __shared__ float  Srow[NROWS];         // softmax denominators
  __shared__ float  S2row[NROWS];        // shrink-sum per row

  const int tid  = threadIdx.x;
  const int n0   = blockIdx.x * NROWS;
  const int lane = tid & 63;
  const int wave = tid >> 6;
  const int quad = lane >> 4;
  const int col  = lane & 15;

  // ---- phase 1: z_norm -> zs (nontemporal z read, read-once stream) ----
  {
    const int r  = tid >> 3;
    const int c0 = (tid & 7) * 32;
    const float* zp = z + (size_t)(n0 + r) * DDIM + c0;
    float v[32];
    #pragma unroll
    for (int k = 0; k < 8; ++k) {
      const f32x4 q = __builtin_nontemporal_load((const f32x4*)(zp + 4 * k));
      v[4*k+0] = q.x; v[4*k+1] = q.y; v[4*k+2] = q.z; v[4*k+3] = q.w;
    }
    float s = 0.f;
    #pragma unroll
    for (int k = 0; k < 32; ++k) s += v[k] * v[k];
    #pragma unroll
    for (int m = 1; m < 8; m <<= 1) s += __shfl_xor(s, m, 64);
    const float scale = 1.0f / (sqrtf(s) + EPS_NORM);
    #pragma unroll
    for (int k = 0; k < 32; ++k) zs[r][c0 + k] = (__bf16)(v[k] * scale);
  }

  // ---- zero this block's z_hat rows now (nt); cold path atomically adds ----
  {
    const f32x4 zero4 = {0.f, 0.f, 0.f, 0.f};
    f32x4* oz = (f32x4*)(outz + (size_t)n0 * DDIM);
    #pragma unroll
    for (int k = 0; k < 8; ++k)
      __builtin_nontemporal_store(zero4, &oz[tid + 256 * k]);
  }
  __syncthreads();

  // ---- A fragments for both row-groups ----
  bf16x8 af[2][8];
  #pragma unroll
  for (int rg = 0; rg < 2; ++rg)
    #pragma unroll
    for (int kc = 0; kc < 8; ++kc)
      af[rg][kc] = *(const bf16x8*)&zs[rg * 16 + col][kc * 32 + quad * 8];

  const int t0 = wave * 32;

  // ---- sweep 1: S = sum(exp(sim)) per row ----
  float S[2][4] = {{0.f,0.f,0.f,0.f},{0.f,0.f,0.f,0.f}};
  for (int i = 0; i < 32; ++i) {
    const int t = t0 + i;
    if (t >= MT) break;                      // wave-uniform
    const __bf16* bp = mnorm + (size_t)(t * 16 + col) * DDIM + quad * 8;
    bf16x8 b[8];
    #pragma unroll
    for (int kc = 0; kc < 8; ++kc) b[kc] = *(const bf16x8*)(bp + kc * 32);
    #pragma unroll
    for (int rg = 0; rg < 2; ++rg) {
      f32x4 c = (f32x4){0.f, 0.f, 0.f, 0.f};
      #pragma unroll
      for (int kc = 0; kc < 8; ++kc)
        c = __builtin_amdgcn_mfma_f32_16x16x32_bf16(af[rg][kc], b[kc], c, 0, 0, 0);
      #pragma unroll
      for (int j = 0; j < 4; ++j) S[rg][j] += __expf(c[j]);
    }
  }
  #pragma unroll
  for (int rg = 0; rg < 2; ++rg)
    #pragma unroll
    for (int j = 0; j < 4; ++j) {
      #pragma unroll
      for (int m = 1; m < 16; m <<= 1) S[rg][j] += __shfl_xor(S[rg][j], m, 64);
      if (col == 0) red[wave][rg * 16 + quad * 4 + j] = S[rg][j];
    }
  __syncthreads();
  if (tid < NROWS) Srow[tid] = red[0][tid] + red[1][tid] + red[2][tid] + red[3][tid];
  __syncthreads();

  float invS[2][4];
  #pragma unroll
  for (int rg = 0; rg < 2; ++rg)
    #pragma unroll
    for (int j = 0; j < 4; ++j) invS[rg][j] = 1.0f / Srow[rg * 16 + quad * 4 + j];

  // ---- sweep 2: recompute sim; w2 + S2 + nt-store w2 (== w_hat if S2==0) --
  float S2[2][4] = {{0.f,0.f,0.f,0.f},{0.f,0.f,0.f,0.f}};
  for (int i = 0; i < 32; ++i) {
    const int t = t0 + i;
    if (t >= MT) break;
    const __bf16* bp = mnorm + (size_t)(t * 16 + col) * DDIM + quad * 8;
    bf16x8 b[8];
    #pragma unroll
    for (int kc = 0; kc < 8; ++kc) b[kc] = *(const bf16x8*)(bp + kc * 32);
    #pragma unroll
    for (int rg = 0; rg < 2; ++rg) {
      f32x4 c = (f32x4){0.f, 0.f, 0.f, 0.f};
      #pragma unroll
      for (int kc = 0; kc < 8; ++kc)
        c = __builtin_amdgcn_mfma_f32_16x16x32_bf16(af[rg][kc], b[kc], c, 0, 0, 0);
      #pragma unroll
      for (int j = 0; j < 4; ++j) {
        const float w = __expf(c[j]) * invS[rg][j];
        const float d = w - LAMB;
        const float w2 = (d > 0.f) ? (d * w / (d + EPS_SHRINK)) : 0.f;
        S2[rg][j] += w2;
        __builtin_nontemporal_store(
            w2, outw + (size_t)(n0 + rg * 16 + quad * 4 + j) * MDIM + t * 16 + col);
      }
    }
  }
  #pragma unroll
  for (int rg = 0; rg < 2; ++rg)
    #pragma unroll
    for (int j = 0; j < 4; ++j) {
      #pragma unroll
      for (int m = 1; m < 16; m <<= 1) S2[rg][j] += __shfl_xor(S2[rg][j], m, 64);
      if (col == 0) red[wave][rg * 16 + quad * 4 + j] = S2[rg][j];
    }
  __syncthreads();
  if (tid < NROWS) S2row[tid] = red[0][tid] + red[1][tid] + red[2][tid] + red[3][tid];
  __syncthreads();

  float totS2 = 0.f;
  #pragma unroll
  for (int r = 0; r < NROWS; ++r) totS2 += S2row[r];

  // ---- cold path: only if some weight survived shrink (exact general case).
  // Re-read stored w2, scale to w_hat, rewrite; accumulate z_hat via global
  // atomics into the pre-zeroed outz rows (block-local rows, no races).
  if (totS2 > 0.f) {
    #pragma unroll 1
    for (int i = 0; i < 32; ++i) {
      const int t = t0 + i;
      if (t >= MT) break;
      #pragma unroll 1
      for (int rg = 0; rg < 2; ++rg)
        #pragma unroll 1
        for (int j = 0; j < 4; ++j) {
          const int r = rg * 16 + quad * 4 + j;
          const float rs2 = 1.0f / (S2row[r] + EPS_SHRINK);
          const int mcol = t * 16 + col;
          float* p = outw + (size_t)(n0 + r) * MDIM + mcol;
          const float wh = *p * rs2;   // rows w/ S2==0: 0 * big == 0, exact
          *p = wh;
          if (wh != 0.f) {
            const float* mrow = mem + (size_t)mcol * DDIM;
            float* zr = outz + (size_t)(n0 + r) * DDIM;
            #pragma unroll 1
            for (int dd = 0; dd < DDIM; ++dd) atomicAdd(&zr[dd], wh * mrow[dd]);
          }
        }
    }
  }
}

extern "C" void kernel_launch(void* const* d_in, const int* in_sizes, int n_in,
                              void* d_out, int out_size, void* d_ws, size_t ws_size,
                              hipStream_t stream) {
  const float* z   = (const float*)d_in[0];
  const float* mem = (const float*)d_in[1];
  const int N = in_sizes[0] / DDIM;           // 65536
  float* outz = (float*)d_out;                // [N, D]
  float* outw = outz + (size_t)N * DDIM;      // [N, M]
  __bf16* mnorm = (__bf16*)d_ws;              // [MPAD, D] bf16 = 1 MiB

  hipLaunchKernelGGL(norm_mem_k, dim3(MPAD), dim3(DDIM), 0, stream, mem, mnorm);
  hipLaunchKernelGGL(fused_k, dim3(N / NROWS), dim3(256), 0, stream,
                     z, mnorm, mem, outz, outw);
}

// Round 5
// 1199.534 us; speedup vs baseline: 1.2822x; 1.2822x over previous
//
#include <hip/hip_runtime.h>
#include <stdint.h>

// MemoryModule: z[N=65536,D=256], memory[M=2000,D=256] (fp32)
//   z_norm, m_norm = row-L2-normalize (eps added to norm)
//   sim = z_norm @ m_norm^T; w = softmax(sim, axis=1)
//   w2 = relu(w-lamb)*w/(|w-lamb|+1e-12); w_hat = w2/(sum w2 + 1e-12)
//   z_hat = w_hat @ memory
// d_out = [z_hat (N*D) | w_hat (N*M)] fp32
//
// R4: latency/MLP-bound fix. R2 structure + small LDS (17.5KB) +
// __launch_bounds__(256,4) (VGPR cap 128 -> no spill, 4 blocks/CU) +
// uniform trip counts + 2-tile unroll for doubled outstanding loads.
// Softmax max-subtraction dropped: |sim|<=1 (cosine), exp in [e^-1, e].

typedef float  f32x4  __attribute__((ext_vector_type(4)));
typedef __bf16 bf16x8 __attribute__((ext_vector_type(8)));

#define DDIM 256
#define MDIM 2000
#define MT   125          // 2000 / 16 m-tiles
#define MPAD 2048
#define NROWS 32          // z-rows per block (2 row-groups of 16)
#define LAMB 0.002f
#define EPS_NORM 1e-10f
#define EPS_SHRINK 1e-12f

// ---------------- kernel 1: memory -> bf16 m_norm (padded to MPAD rows) ----
__global__ __launch_bounds__(256) void norm_mem_k(const float* __restrict__ mem,
                                                  __bf16* __restrict__ mnorm) {
  const int row = blockIdx.x;
  const int t   = threadIdx.x;
  if (row >= MDIM) { mnorm[(size_t)row * DDIM + t] = (__bf16)0.0f; return; }
  float x = mem[(size_t)row * DDIM + t];
  float s = x * x;
  #pragma unroll
  for (int m = 1; m < 64; m <<= 1) s += __shfl_xor(s, m, 64);
  __shared__ float wsum[4];
  if ((t & 63) == 0) wsum[t >> 6] = s;
  __syncthreads();
  s = wsum[0] + wsum[1] + wsum[2] + wsum[3];
  const float scale = 1.0f / (sqrtf(s) + EPS_NORM);
  mnorm[(size_t)row * DDIM + t] = (__bf16)(x * scale);
}

// ---------------- kernel 2: fused, 32 rows/block, 2 sweeps ----------------
// 4 waves split 125 m-tiles contiguously (32/32/32/29). Per tile:
// B[8] (16 rows x K=256 bf16) from L2, MFMA vs 2 row-group A-frags (regs).
// MFMA C layout (16x16x32): col = lane&15 (m), row = quad*4 + reg (n).
__global__ __launch_bounds__(256, 4) void fused_k(
    const float* __restrict__ z, const __bf16* __restrict__ mnorm,
    const float* __restrict__ mem, float* __restrict__ outz,
    float* __restrict__ outw) {
  __shared__ __bf16 zs[NROWS][264];      // z_norm staging (+8 pad)  16.9 KB
  __shared__ float  red[4][NROWS];
  __shared__ float  Srow[NROWS];
  __shared__ float  S2row[NROWS];

  const int tid  = threadIdx.x;
  const int n0   = blockIdx.x * NROWS;
  const int lane = tid & 63;
  const int wave = tid >> 6;
  const int quad = lane >> 4;
  const int col  = lane & 15;

  // ---- phase 1: z_norm -> zs ----
  {
    const int r  = tid >> 3;
    const int c0 = (tid & 7) * 32;
    const float* zp = z + (size_t)(n0 + r) * DDIM + c0;
    float v[32];
    #pragma unroll
    for (int k = 0; k < 8; ++k) {
      const float4 q = *(const float4*)(zp + 4 * k);
      v[4*k+0] = q.x; v[4*k+1] = q.y; v[4*k+2] = q.z; v[4*k+3] = q.w;
    }
    float s = 0.f;
    #pragma unroll
    for (int k = 0; k < 32; ++k) s += v[k] * v[k];
    #pragma unroll
    for (int m = 1; m < 8; m <<= 1) s += __shfl_xor(s, m, 64);
    const float scale = 1.0f / (sqrtf(s) + EPS_NORM);
    #pragma unroll
    for (int k = 0; k < 32; ++k) zs[r][c0 + k] = (__bf16)(v[k] * scale);
  }

  // ---- zero this block's z_hat rows (cold path atomically adds later) ----
  {
    const f32x4 zero4 = {0.f, 0.f, 0.f, 0.f};
    f32x4* oz = (f32x4*)(outz + (size_t)n0 * DDIM);
    #pragma unroll
    for (int k = 0; k < 8; ++k) oz[tid + 256 * k] = zero4;
  }
  __syncthreads();

  // ---- A fragments for both row-groups ----
  bf16x8 af[2][8];
  #pragma unroll
  for (int rg = 0; rg < 2; ++rg)
    #pragma unroll
    for (int kc = 0; kc < 8; ++kc)
      af[rg][kc] = *(const bf16x8*)&zs[rg * 16 + col][kc * 32 + quad * 8];

  const int t0    = wave * 32;
  const int ntile = (MT - t0) < 32 ? (MT - t0) : 32;   // 32,32,32,29

  // ---- sweep 1: S = sum(exp(sim)) per row; 2 tiles/iter for MLP ----
  float S[2][4] = {{0.f,0.f,0.f,0.f},{0.f,0.f,0.f,0.f}};
  {
    int i = 0;
    for (; i + 2 <= ntile; i += 2) {
      const __bf16* bp0 = mnorm + (size_t)((t0 + i) * 16 + col) * DDIM + quad * 8;
      const __bf16* bp1 = bp0 + 16 * DDIM;
      bf16x8 b0[8], b1[8];
      #pragma unroll
      for (int kc = 0; kc < 8; ++kc) b0[kc] = *(const bf16x8*)(bp0 + kc * 32);
      #pragma unroll
      for (int kc = 0; kc < 8; ++kc) b1[kc] = *(const bf16x8*)(bp1 + kc * 32);
      #pragma unroll
      for (int rg = 0; rg < 2; ++rg) {
        f32x4 c0 = (f32x4){0.f, 0.f, 0.f, 0.f};
        f32x4 c1 = (f32x4){0.f, 0.f, 0.f, 0.f};
        #pragma unroll
        for (int kc = 0; kc < 8; ++kc) {
          c0 = __builtin_amdgcn_mfma_f32_16x16x32_bf16(af[rg][kc], b0[kc], c0, 0, 0, 0);
          c1 = __builtin_amdgcn_mfma_f32_16x16x32_bf16(af[rg][kc], b1[kc], c1, 0, 0, 0);
        }
        #pragma unroll
        for (int j = 0; j < 4; ++j) S[rg][j] += __expf(c0[j]) + __expf(c1[j]);
      }
    }
    if (i < ntile) {
      const __bf16* bp = mnorm + (size_t)((t0 + i) * 16 + col) * DDIM + quad * 8;
      bf16x8 b[8];
      #pragma unroll
      for (int kc = 0; kc < 8; ++kc) b[kc] = *(const bf16x8*)(bp + kc * 32);
      #pragma unroll
      for (int rg = 0; rg < 2; ++rg) {
        f32x4 c = (f32x4){0.f, 0.f, 0.f, 0.f};
        #pragma unroll
        for (int kc = 0; kc < 8; ++kc)
          c = __builtin_amdgcn_mfma_f32_16x16x32_bf16(af[rg][kc], b[kc], c, 0, 0, 0);
        #pragma unroll
        for (int j = 0; j < 4; ++j) S[rg][j] += __expf(c[j]);
      }
    }
  }
  #pragma unroll
  for (int rg = 0; rg < 2; ++rg)
    #pragma unroll
    for (int j = 0; j < 4; ++j) {
      #pragma unroll
      for (int m = 1; m < 16; m <<= 1) S[rg][j] += __shfl_xor(S[rg][j], m, 64);
      if (col == 0) red[wave][rg * 16 + quad * 4 + j] = S[rg][j];
    }
  __syncthreads();
  if (tid < NROWS) Srow[tid] = red[0][tid] + red[1][tid] + red[2][tid] + red[3][tid];
  __syncthreads();

  float invS[2][4];
  #pragma unroll
  for (int rg = 0; rg < 2; ++rg)
    #pragma unroll
    for (int j = 0; j < 4; ++j) invS[rg][j] = 1.0f / Srow[rg * 16 + quad * 4 + j];

  // ---- sweep 2: recompute sim; w2 + S2 + store w2 (== w_hat if S2==0) ----
  float S2[2][4] = {{0.f,0.f,0.f,0.f},{0.f,0.f,0.f,0.f}};
  {
    int i = 0;
    for (; i + 2 <= ntile; i += 2) {
      const int ta = t0 + i, tb = t0 + i + 1;
      const __bf16* bp0 = mnorm + (size_t)(ta * 16 + col) * DDIM + quad * 8;
      const __bf16* bp1 = bp0 + 16 * DDIM;
      bf16x8 b0[8], b1[8];
      #pragma unroll
      for (int kc = 0; kc < 8; ++kc) b0[kc] = *(const bf16x8*)(bp0 + kc * 32);
      #pragma unroll
      for (int kc = 0; kc < 8; ++kc) b1[kc] = *(const bf16x8*)(bp1 + kc * 32);
      #pragma unroll
      for (int rg = 0; rg < 2; ++rg) {
        f32x4 c0 = (f32x4){0.f, 0.f, 0.f, 0.f};
        f32x4 c1 = (f32x4){0.f, 0.f, 0.f, 0.f};
        #pragma unroll
        for (int kc = 0; kc < 8; ++kc) {
          c0 = __builtin_amdgcn_mfma_f32_16x16x32_bf16(af[rg][kc], b0[kc], c0, 0, 0, 0);
          c1 = __builtin_amdgcn_mfma_f32_16x16x32_bf16(af[rg][kc], b1[kc], c1, 0, 0, 0);
        }
        float* orow = outw + (size_t)(n0 + rg * 16 + quad * 4) * MDIM + col;
        #pragma unroll
        for (int j = 0; j < 4; ++j) {
          const float w0 = __expf(c0[j]) * invS[rg][j];
          const float d0 = w0 - LAMB;
          const float w20 = (d0 > 0.f) ? (d0 * w0 / (d0 + EPS_SHRINK)) : 0.f;
          const float w1 = __expf(c1[j]) * invS[rg][j];
          const float d1 = w1 - LAMB;
          const float w21 = (d1 > 0.f) ? (d1 * w1 / (d1 + EPS_SHRINK)) : 0.f;
          S2[rg][j] += w20 + w21;
          orow[(size_t)j * MDIM + ta * 16] = w20;
          orow[(size_t)j * MDIM + tb * 16] = w21;
        }
      }
    }
    if (i < ntile) {
      const int ta = t0 + i;
      const __bf16* bp = mnorm + (size_t)(ta * 16 + col) * DDIM + quad * 8;
      bf16x8 b[8];
      #pragma unroll
      for (int kc = 0; kc < 8; ++kc) b[kc] = *(const bf16x8*)(bp + kc * 32);
      #pragma unroll
      for (int rg = 0; rg < 2; ++rg) {
        f32x4 c = (f32x4){0.f, 0.f, 0.f, 0.f};
        #pragma unroll
        for (int kc = 0; kc < 8; ++kc)
          c = __builtin_amdgcn_mfma_f32_16x16x32_bf16(af[rg][kc], b[kc], c, 0, 0, 0);
        float* orow = outw + (size_t)(n0 + rg * 16 + quad * 4) * MDIM + col;
        #pragma unroll
        for (int j = 0; j < 4; ++j) {
          const float w = __expf(c[j]) * invS[rg][j];
          const float d = w - LAMB;
          const float w2 = (d > 0.f) ? (d * w / (d + EPS_SHRINK)) : 0.f;
          S2[rg][j] += w2;
          orow[(size_t)j * MDIM + ta * 16] = w2;
        }
      }
    }
  }
  #pragma unroll
  for (int rg = 0; rg < 2; ++rg)
    #pragma unroll
    for (int j = 0; j < 4; ++j) {
      #pragma unroll
      for (int m = 1; m < 16; m <<= 1) S2[rg][j] += __shfl_xor(S2[rg][j], m, 64);
      if (col == 0) red[wave][rg * 16 + quad * 4 + j] = S2[rg][j];
    }
  __syncthreads();
  if (tid < NROWS) S2row[tid] = red[0][tid] + red[1][tid] + red[2][tid] + red[3][tid];
  __syncthreads();

  float totS2 = 0.f;
  #pragma unroll
  for (int r = 0; r < NROWS; ++r) totS2 += S2row[r];

  // ---- cold path: only if some weight survived shrink (exact general case).
  // Re-read stored w2, scale to w_hat, rewrite; accumulate z_hat via global
  // atomics into the pre-zeroed outz rows (block-local rows, no races).
  if (totS2 > 0.f) {
    #pragma unroll 1
    for (int i = 0; i < ntile; ++i) {
      const int t = t0 + i;
      #pragma unroll 1
      for (int rg = 0; rg < 2; ++rg)
        #pragma unroll 1
        for (int j = 0; j < 4; ++j) {
          const int r = rg * 16 + quad * 4 + j;
          const float rs2 = 1.0f / (S2row[r] + EPS_SHRINK);
          const int mcol = t * 16 + col;
          float* p = outw + (size_t)(n0 + r) * MDIM + mcol;
          const float wh = *p * rs2;   // rows w/ S2==0: 0 * big == 0, exact
          *p = wh;
          if (wh != 0.f) {
            const float* mrow = mem + (size_t)mcol * DDIM;
            float* zr = outz + (size_t)(n0 + r) * DDIM;
            #pragma unroll 1
            for (int dd = 0; dd < DDIM; ++dd) atomicAdd(&zr[dd], wh * mrow[dd]);
          }
        }
    }
  }
}

extern "C" void kernel_launch(void* const* d_in, const int* in_sizes, int n_in,
                              void* d_out, int out_size, void* d_ws, size_t ws_size,
                              hipStream_t stream) {
  const float* z   = (const float*)d_in[0];
  const float* mem = (const float*)d_in[1];
  const int N = in_sizes[0] / DDIM;           // 65536
  float* outz = (float*)d_out;                // [N, D]
  float* outw = outz + (size_t)N * DDIM;      // [N, M]
  __bf16* mnorm = (__bf16*)d_ws;              // [MPAD, D] bf16 = 1 MiB

  hipLaunchKernelGGL(norm_mem_k, dim3(MPAD), dim3(DDIM), 0, stream, mem, mnorm);
  hipLaunchKernelGGL(fused_k, dim3(N / NROWS), dim3(256), 0, stream,
                     z, mnorm, mem, outz, outw);
}

// Round 6
// 1056.958 us; speedup vs baseline: 1.4552x; 1.1349x over previous
//
#include <hip/hip_runtime.h>
#include <stdint.h>

// MemoryModule: z[N=65536,D=256], memory[M=2000,D=256] (fp32)
//   z_norm, m_norm = row-L2-normalize (eps added to norm)
//   sim = z_norm @ m_norm^T; w = softmax(sim, axis=1)
//   w2 = relu(w-lamb)*w/(|w-lamb|+1e-12); w_hat = w2/(sum w2 + 1e-12)
//   z_hat = w_hat @ memory
// d_out = [z_hat (N*D) | w_hat (N*M)] fp32
//
// R5: R2's register-lean body (VGPR 84 -> 6 waves/SIMD) + small LDS
// (17.9 KB -> 6 blocks/CU fit) = 24 waves/CU, 2x R2 residency. The kernel
// is MLP-bound (R3/R4 proved ~2.1-2.5 TB/s at ~20 waves/CU); no unroll,
// no nt, no VGPR caps beyond R2's (256,3).
// Softmax max-subtraction dropped: |sim|<=1 (cosine), exp in [e^-1, e].

typedef float  f32x4  __attribute__((ext_vector_type(4)));
typedef __bf16 bf16x8 __attribute__((ext_vector_type(8)));

#define DDIM 256
#define MDIM 2000
#define MT   125          // 2000 / 16 m-tiles
#define MPAD 2048
#define NROWS 32          // z-rows per block (2 row-groups of 16)
#define LAMB 0.002f
#define EPS_NORM 1e-10f
#define EPS_SHRINK 1e-12f

// ---------------- kernel 1: memory -> bf16 m_norm (padded to MPAD rows) ----
__global__ __launch_bounds__(256) void norm_mem_k(const float* __restrict__ mem,
                                                  __bf16* __restrict__ mnorm) {
  const int row = blockIdx.x;
  const int t   = threadIdx.x;
  if (row >= MDIM) { mnorm[(size_t)row * DDIM + t] = (__bf16)0.0f; return; }
  float x = mem[(size_t)row * DDIM + t];
  float s = x * x;
  #pragma unroll
  for (int m = 1; m < 64; m <<= 1) s += __shfl_xor(s, m, 64);
  __shared__ float wsum[4];
  if ((t & 63) == 0) wsum[t >> 6] = s;
  __syncthreads();
  s = wsum[0] + wsum[1] + wsum[2] + wsum[3];
  const float scale = 1.0f / (sqrtf(s) + EPS_NORM);
  mnorm[(size_t)row * DDIM + t] = (__bf16)(x * scale);
}

// ---------------- kernel 2: fused, 32 rows/block, 2 sweeps ----------------
// 4 waves split 125 m-tiles contiguously (32/32/32/29). Per tile:
// B[8] (16 rows x K=256 bf16) from L2, MFMA vs 2 row-group A-frags (regs).
// MFMA C layout (16x16x32): col = lane&15 (m), row = quad*4 + reg (n).
__global__ __launch_bounds__(256, 3) void fused_k(
    const float* __restrict__ z, const __bf16* __restrict__ mnorm,
    const float* __restrict__ mem, float* __restrict__ outz,
    float* __restrict__ outw) {
  __shared__ __bf16 zs[NROWS][264];      // z_norm staging (+8 pad)  16.9 KB
  __shared__ float  red[4][NROWS];
  __shared__ float  Srow[NROWS];
  __shared__ float  S2row[NROWS];

  const int tid  = threadIdx.x;
  const int n0   = blockIdx.x * NROWS;
  const int lane = tid & 63;
  const int wave = tid >> 6;
  const int quad = lane >> 4;
  const int col  = lane & 15;

  // ---- phase 1: z_norm -> zs ----
  {
    const int r  = tid >> 3;
    const int c0 = (tid & 7) * 32;
    const float* zp = z + (size_t)(n0 + r) * DDIM + c0;
    float v[32];
    #pragma unroll
    for (int k = 0; k < 8; ++k) {
      const float4 q = *(const float4*)(zp + 4 * k);
      v[4*k+0] = q.x; v[4*k+1] = q.y; v[4*k+2] = q.z; v[4*k+3] = q.w;
    }
    float s = 0.f;
    #pragma unroll
    for (int k = 0; k < 32; ++k) s += v[k] * v[k];
    #pragma unroll
    for (int m = 1; m < 8; m <<= 1) s += __shfl_xor(s, m, 64);
    const float scale = 1.0f / (sqrtf(s) + EPS_NORM);
    #pragma unroll
    for (int k = 0; k < 32; ++k) zs[r][c0 + k] = (__bf16)(v[k] * scale);
  }

  // ---- zero this block's z_hat rows (cold path atomically adds later) ----
  {
    const f32x4 zero4 = {0.f, 0.f, 0.f, 0.f};
    f32x4* oz = (f32x4*)(outz + (size_t)n0 * DDIM);
    #pragma unroll
    for (int k = 0; k < 8; ++k) oz[tid + 256 * k] = zero4;
  }
  __syncthreads();

  // ---- A fragments for both row-groups ----
  bf16x8 af[2][8];
  #pragma unroll
  for (int rg = 0; rg < 2; ++rg)
    #pragma unroll
    for (int kc = 0; kc < 8; ++kc)
      af[rg][kc] = *(const bf16x8*)&zs[rg * 16 + col][kc * 32 + quad * 8];

  const int t0    = wave * 32;
  const int ntile = (MT - t0) < 32 ? (MT - t0) : 32;   // 32,32,32,29

  // ---- sweep 1: S = sum(exp(sim)) per row ----
  float S[2][4] = {{0.f,0.f,0.f,0.f},{0.f,0.f,0.f,0.f}};
  for (int i = 0; i < ntile; ++i) {
    const int t = t0 + i;
    const __bf16* bp = mnorm + (size_t)(t * 16 + col) * DDIM + quad * 8;
    bf16x8 b[8];
    #pragma unroll
    for (int kc = 0; kc < 8; ++kc) b[kc] = *(const bf16x8*)(bp + kc * 32);
    #pragma unroll
    for (int rg = 0; rg < 2; ++rg) {
      f32x4 c = (f32x4){0.f, 0.f, 0.f, 0.f};
      #pragma unroll
      for (int kc = 0; kc < 8; ++kc)
        c = __builtin_amdgcn_mfma_f32_16x16x32_bf16(af[rg][kc], b[kc], c, 0, 0, 0);
      #pragma unroll
      for (int j = 0; j < 4; ++j) S[rg][j] += __expf(c[j]);
    }
  }
  #pragma unroll
  for (int rg = 0; rg < 2; ++rg)
    #pragma unroll
    for (int j = 0; j < 4; ++j) {
      #pragma unroll
      for (int m = 1; m < 16; m <<= 1) S[rg][j] += __shfl_xor(S[rg][j], m, 64);
      if (col == 0) red[wave][rg * 16 + quad * 4 + j] = S[rg][j];
    }
  __syncthreads();
  if (tid < NROWS) Srow[tid] = red[0][tid] + red[1][tid] + red[2][tid] + red[3][tid];
  __syncthreads();

  float invS[2][4];
  #pragma unroll
  for (int rg = 0; rg < 2; ++rg)
    #pragma unroll
    for (int j = 0; j < 4; ++j) invS[rg][j] = 1.0f / Srow[rg * 16 + quad * 4 + j];

  // ---- sweep 2: recompute sim; w2 + S2 + store w2 (== w_hat if S2==0) ----
  float S2[2][4] = {{0.f,0.f,0.f,0.f},{0.f,0.f,0.f,0.f}};
  for (int i = 0; i < ntile; ++i) {
    const int t = t0 + i;
    const __bf16* bp = mnorm + (size_t)(t * 16 + col) * DDIM + quad * 8;
    bf16x8 b[8];
    #pragma unroll
    for (int kc = 0; kc < 8; ++kc) b[kc] = *(const bf16x8*)(bp + kc * 32);
    #pragma unroll
    for (int rg = 0; rg < 2; ++rg) {
      f32x4 c = (f32x4){0.f, 0.f, 0.f, 0.f};
      #pragma unroll
      for (int kc = 0; kc < 8; ++kc)
        c = __builtin_amdgcn_mfma_f32_16x16x32_bf16(af[rg][kc], b[kc], c, 0, 0, 0);
      float* orow = outw + (size_t)(n0 + rg * 16 + quad * 4) * MDIM + t * 16 + col;
      #pragma unroll
      for (int j = 0; j < 4; ++j) {
        const float w = __expf(c[j]) * invS[rg][j];
        const float d = w - LAMB;
        const float w2 = (d > 0.f) ? (d * w / (d + EPS_SHRINK)) : 0.f;
        S2[rg][j] += w2;
        orow[(size_t)j * MDIM] = w2;
      }
    }
  }
  #pragma unroll
  for (int rg = 0; rg < 2; ++rg)
    #pragma unroll
    for (int j = 0; j < 4; ++j) {
      #pragma unroll
      for (int m = 1; m < 16; m <<= 1) S2[rg][j] += __shfl_xor(S2[rg][j], m, 64);
      if (col == 0) red[wave][rg * 16 + quad * 4 + j] = S2[rg][j];
    }
  __syncthreads();
  if (tid < NROWS) S2row[tid] = red[0][tid] + red[1][tid] + red[2][tid] + red[3][tid];
  __syncthreads();

  float totS2 = 0.f;
  #pragma unroll
  for (int r = 0; r < NROWS; ++r) totS2 += S2row[r];

  // ---- cold path: only if some weight survived shrink (exact general case).
  // Re-read stored w2, scale to w_hat, rewrite; accumulate z_hat via global
  // atomics into the pre-zeroed outz rows (block-local rows, no races).
  if (totS2 > 0.f) {
    #pragma unroll 1
    for (int i = 0; i < ntile; ++i) {
      const int t = t0 + i;
      #pragma unroll 1
      for (int rg = 0; rg < 2; ++rg)
        #pragma unroll 1
        for (int j = 0; j < 4; ++j) {
          const int r = rg * 16 + quad * 4 + j;
          const float rs2 = 1.0f / (S2row[r] + EPS_SHRINK);
          const int mcol = t * 16 + col;
          float* p = outw + (size_t)(n0 + r) * MDIM + mcol;
          const float wh = *p * rs2;   // rows w/ S2==0: 0 * big == 0, exact
          *p = wh;
          if (wh != 0.f) {
            const float* mrow = mem + (size_t)mcol * DDIM;
            float* zr = outz + (size_t)(n0 + r) * DDIM;
            #pragma unroll 1
            for (int dd = 0; dd < DDIM; ++dd) atomicAdd(&zr[dd], wh * mrow[dd]);
          }
        }
    }
  }
}

extern "C" void kernel_launch(void* const* d_in, const int* in_sizes, int n_in,
                              void* d_out, int out_size, void* d_ws, size_t ws_size,
                              hipStream_t stream) {
  const float* z   = (const float*)d_in[0];
  const float* mem = (const float*)d_in[1];
  const int N = in_sizes[0] / DDIM;           // 65536
  float* outz = (float*)d_out;                // [N, D]
  float* outw = outz + (size_t)N * DDIM;      // [N, M]
  __bf16* mnorm = (__bf16*)d_ws;              // [MPAD, D] bf16 = 1 MiB

  hipLaunchKernelGGL(norm_mem_k, dim3(MPAD), dim3(DDIM), 0, stream, mem, mnorm);
  hipLaunchKernelGGL(fused_k, dim3(N / NROWS), dim3(256), 0, stream,
                     z, mnorm, mem, outz, outw);
}